// Round 4
// baseline (411.412 us; speedup 1.0000x reference)
//
#include <hip/hip_runtime.h>
#include <math.h>

#define DELTA_ 1e-6f
#define IFACE_ 471
#define XI_STRIDE 480

// workspace offsets (in floats)
#define OFF_XI    0            // 32*480
#define OFF_RKN   15360        // 32*4*64
#define OFF_RS    23552        // 32*4
#define OFF_ER    23680        // 32*64
#define OFF_WV    25728        // 32*64
#define OFF_RM    27776        // 32*12
#define OFF_WW    28160        // 32*1024
#define OFF_WWRW  60928        // 32*4*1024
#define OFF_PRD   192000       // 32*4
#define OFF_WRD   192128       // 32*4
#define OFF_INVN  192256       // 32*1024
#define OFF_DIAG  225024       // 32*1024
#define OFF_NM    257792       // 32*1024*64
#define OFF_RAP   2354944      // 32*4cc*4r*1024
#define OFF_RBP   2879232      // 32*4cc*4r*1024
#define OFF_SAP   3403520      // 32*16rc*4r*1024
#define OFF_SBP   5500672      // 32*16rc*4r*1024
// total 7597824 floats = 29 MB

__device__ __forceinline__ float sigm_(float x){ return 1.f/(1.f+expf(-x)); }
__device__ __forceinline__ float softp_(float x){ return fmaxf(x,0.f)+log1pf(expf(-fabsf(x))); }
__device__ __forceinline__ float dot4_(float4 a, float4 b){ return a.x*b.x+a.y*b.y+a.z*b.z+a.w*b.w; }

// ---------------- K1: xi = x @ W_if + b_if ----------------
__global__ __launch_bounds__(256) void k_xi(const float* __restrict__ x,
    const float* __restrict__ W, const float* __restrict__ bias,
    float* __restrict__ xi) {
  int b = blockIdx.x;
  int j0 = blockIdx.y*64;
  int t = threadIdx.x;
  int jl = t & 63, kq = t >> 6;
  __shared__ __align__(16) float sx[1024];
  __shared__ float s_part[256];
  for (int q=t; q<256; q+=256) ((float4*)sx)[q] = ((const float4*)(x + b*1024))[q];
  __syncthreads();
  int j = j0 + jl;
  int jc = j < IFACE_ ? j : IFACE_-1;
  float acc = 0.f;
  const float* Wp = W + (size_t)kq*256*IFACE_ + jc;
  #pragma unroll 4
  for (int k=0;k<256;++k) acc += sx[kq*256+k]*Wp[(size_t)k*IFACE_];
  s_part[t] = acc;
  __syncthreads();
  if (t < 64 && (j0+t) < IFACE_) {
    xi[b*XI_STRIDE + j0+t] = s_part[t]+s_part[64+t]+s_part[128+t]+s_part[192+t] + bias[j0+t];
  }
}

// ---------------- K2: per-batch: activations, wcw, usage, sort/alloc, ww ----------------
__global__ __launch_bounds__(256) void k_batch(
    const float* __restrict__ xi, const float* __restrict__ memory,
    const float* __restrict__ usage, const float* __restrict__ read_w,
    const float* __restrict__ write_w, const float* __restrict__ precedence,
    float* __restrict__ rkn, float* __restrict__ rs, float* __restrict__ er,
    float* __restrict__ wv, float* __restrict__ rm, float* __restrict__ ww_out,
    float* __restrict__ wwrw, float* __restrict__ prd, float* __restrict__ wrd) {
  int b = blockIdx.x; int t = threadIdx.x;
  int lane = t & 63; int wave = t >> 6;
  __shared__ float s_act[472];
  __shared__ __align__(16) float s_key[64];
  __shared__ float s_wcw[1024];
  __shared__ unsigned long long s_k64[1024];
  __shared__ float s_ps[1024];
  __shared__ float s_alloc[1024];
  __shared__ float s_red[32];
  __shared__ float s_bc[2];

  for (int q = t; q < IFACE_; q += 256) {
    float v = xi[b*XI_STRIDE+q];
    float a;
    if      (q < 256) a = tanhf(v);
    else if (q < 260) a = softp_(v);
    else if (q < 324) a = tanhf(v);
    else if (q < 325) a = softp_(v);
    else if (q < 389) a = sigm_(v);
    else if (q < 453) a = tanhf(v);
    else if (q < 459) a = sigm_(v);
    else              a = v;
    s_act[q] = a;
  }
  __syncthreads();
  if (t < 4) {
    float m0=s_act[459+3*t], m1=s_act[460+3*t], m2=s_act[461+3*t];
    float mx=fmaxf(m0,fmaxf(m1,m2));
    float e0=expf(m0-mx), e1=expf(m1-mx), e2=expf(m2-mx);
    float s=e0+e1+e2;
    rm[b*12+3*t+0]=e0/s; rm[b*12+3*t+1]=e1/s; rm[b*12+3*t+2]=e2/s;
  }
  if (t < 64) { er[b*64+t]=s_act[325+t]; wv[b*64+t]=s_act[389+t]; }
  {
    int r = wave;
    float v = s_act[r*64+lane];
    float ss = v*v;
    for (int off=32; off; off>>=1) ss += __shfl_xor(ss, off);
    rkn[((size_t)b*4+r)*64+lane] = v / (sqrtf(ss)+DELTA_);
    if (lane==0) rs[b*4+r] = s_act[256+r];
  }
  if (wave==0) {
    float v = s_act[260+lane];
    float ss=v*v;
    for (int off=32; off; off>>=1) ss += __shfl_xor(ss, off);
    s_key[lane] = v/(sqrtf(ss)+DELTA_);
  }
  __syncthreads();
  float wstr = s_act[324], agv = s_act[457], wgv = s_act[458];

  for (int n=t; n<1024; n+=256) {
    const float4* row = (const float4*)(memory + ((size_t)b*1024+n)*64);
    float dot=0.f, nn2=0.f;
    #pragma unroll
    for (int w4=0; w4<16; ++w4) {
      float4 m4 = row[w4];
      float4 k4 = ((const float4*)s_key)[w4];
      dot += dot4_(m4,k4);
      nn2 += dot4_(m4,m4);
    }
    s_wcw[n] = dot/(sqrtf(nn2)+DELTA_) * wstr;
  }
  __syncthreads();
  {
    float lm=-1e30f;
    for (int n=t;n<1024;n+=256) lm=fmaxf(lm,s_wcw[n]);
    for (int off=32;off;off>>=1) lm=fmaxf(lm,__shfl_xor(lm,off));
    if (lane==0) s_red[wave]=lm;
    __syncthreads();
    if (t==0) s_bc[0]=fmaxf(fmaxf(s_red[0],s_red[1]),fmaxf(s_red[2],s_red[3]));
    __syncthreads();
    float mx=s_bc[0], ls=0.f;
    for (int n=t;n<1024;n+=256){ float e=expf(s_wcw[n]-mx); s_wcw[n]=e; ls+=e; }
    for (int off=32;off;off>>=1) ls+=__shfl_xor(ls,off);
    if (lane==0) s_red[wave]=ls;
    __syncthreads();
    if (t==0) s_bc[1]=s_red[0]+s_red[1]+s_red[2]+s_red[3];
    __syncthreads();
    float inv=1.f/s_bc[1];
    for (int n=t;n<1024;n+=256) s_wcw[n]*=inv;
  }
  __syncthreads();

  for (int n=t; n<1024; n+=256) {
    float us = usage[b*1024+n];
    float wwi = write_w[b*1024+n];
    float u = us + (1.f-us)*wwi;
    float psi = 1.f;
    #pragma unroll
    for (int r=0;r<4;++r) psi *= (1.f - s_act[453+r]*read_w[((size_t)b*4+r)*1024+n]);
    u *= psi;
    u = DELTA_ + (1.f-DELTA_)*u;
    unsigned int ub = __float_as_uint(u);
    s_k64[n] = ((unsigned long long)ub<<32) | (unsigned int)n;
  }

  for (int k=2; k<=1024; k<<=1) {
    for (int j=k>>1; j>0; j>>=1) {
      __syncthreads();
      for (int idx=t; idx<1024; idx+=256) {
        int partner = idx ^ j;
        if (partner > idx) {
          unsigned long long a=s_k64[idx], c=s_k64[partner];
          bool asc = ((idx & k) == 0);
          bool sw = asc ? (a > c) : (a < c);
          if (sw) { s_k64[idx]=c; s_k64[partner]=a; }
        }
      }
    }
  }
  __syncthreads();

  for (int n=t;n<1024;n+=256) s_ps[n] = __uint_as_float((unsigned int)(s_k64[n]>>32));
  __syncthreads();
  for (int off=1; off<1024; off<<=1) {
    float tmp[4];
    #pragma unroll
    for (int m=0;m<4;++m){ int n=t+256*m; tmp[m] = (n>=off)? s_ps[n-off] : 1.f; }
    __syncthreads();
    #pragma unroll
    for (int m=0;m<4;++m){ int n=t+256*m; s_ps[n] *= tmp[m]; }
    __syncthreads();
  }
  for (int n=t;n<1024;n+=256) {
    unsigned long long kv = s_k64[n];
    float su = __uint_as_float((unsigned int)(kv>>32));
    int oi = (int)(kv & 0xffffffffu);
    float prod = (n==0)?1.f:s_ps[n-1];
    s_alloc[oi] = (1.f-su)*prod;
  }
  __syncthreads();

  float pp[4]={0,0,0,0}, wp[4]={0,0,0,0};
  for (int n=t;n<1024;n+=256) {
    float w_ = wgv*(agv*s_alloc[n] + (1.f-agv)*s_wcw[n]);
    ww_out[b*1024+n]=w_;
    float pn = precedence[b*1024+n];
    #pragma unroll
    for (int r=0;r<4;++r){
      float rwv = read_w[((size_t)b*4+r)*1024+n];
      wwrw[((size_t)b*4+r)*1024+n] = w_*rwv;
      pp[r] += pn*rwv;
      wp[r] += w_*rwv;
    }
  }
  #pragma unroll
  for (int r=0;r<4;++r){
    for (int off=32;off;off>>=1){ pp[r]+=__shfl_xor(pp[r],off); wp[r]+=__shfl_xor(wp[r],off); }
  }
  if (lane==0){
    #pragma unroll
    for (int r=0;r<4;++r){ s_red[wave*8+r]=pp[r]; s_red[wave*8+4+r]=wp[r]; }
  }
  __syncthreads();
  if (t<4)              prd[b*4+t]   = s_red[t]+s_red[8+t]+s_red[16+t]+s_red[24+t];
  else if (t<8){ int r=t-4; wrd[b*4+r] = s_red[4+r]+s_red[12+r]+s_red[20+r]+s_red[28+r]; }
}

// ---------------- K3: new memory + row inverse norms ----------------
__global__ __launch_bounds__(256) void k_newmem(const float* __restrict__ memory,
    const float* __restrict__ ww, const float* __restrict__ er,
    const float* __restrict__ wv, float* __restrict__ newmem, float* __restrict__ invn) {
  int b = blockIdx.x;
  int n0 = blockIdx.y*64;
  int t = threadIdx.x;
  int lane16 = t & 15, rl = t >> 4;
  __shared__ float s_ww[64];
  __shared__ __align__(16) float s_er[64];
  __shared__ __align__(16) float s_wv[64];
  if (t < 64) s_ww[t] = ww[b*1024 + n0 + t];
  else if (t < 128) s_er[t-64] = er[b*64 + (t-64)];
  else if (t < 192) s_wv[t-128] = wv[b*64 + (t-128)];
  __syncthreads();
  float4 e4 = ((const float4*)s_er)[lane16];
  float4 v4 = ((const float4*)s_wv)[lane16];
  #pragma unroll
  for (int p=0;p<4;++p) {
    int rloc = p*16 + rl;
    int row = n0 + rloc;
    float wn = s_ww[rloc];
    size_t i4 = ((size_t)b*1024+row)*16 + lane16;
    float4 m4 = ((const float4*)memory)[i4];
    float4 nv;
    nv.x = m4.x*(1.f-wn*e4.x) + wn*v4.x;
    nv.y = m4.y*(1.f-wn*e4.y) + wn*v4.y;
    nv.z = m4.z*(1.f-wn*e4.z) + wn*v4.z;
    nv.w = m4.w*(1.f-wn*e4.w) + wn*v4.w;
    ((float4*)newmem)[i4] = nv;
    float ss = dot4_(nv,nv);
    ss += __shfl_xor(ss,1); ss += __shfl_xor(ss,2);
    ss += __shfl_xor(ss,4); ss += __shfl_xor(ss,8);
    if (lane16==0) invn[b*1024+row] = 1.f/(sqrtf(ss)+DELTA_);
  }
}

// ---------------- K4: single-pass L scan: row-dots + col-sums + diag ----------------
// grid (32 b, 16 rc, 4 cc). Block: 64 rows x 256 cols panel.
// wave tq handles rows i0+16*tq .. +15; lane tl owns float4 cols (cc*256 + 4*tl).
__global__ __launch_bounds__(256) void k_scan(const float* __restrict__ L,
    const float* __restrict__ read_w, const float* __restrict__ wwrw,
    float* __restrict__ RAp, float* __restrict__ RBp,
    float* __restrict__ SAp, float* __restrict__ SBp,
    float* __restrict__ diag) {
  int b = blockIdx.x, rc = blockIdx.y, cc = blockIdx.z;
  int i0 = rc*64;
  int t = threadIdx.x;
  int tq = t>>6, tl = t&63;
  // smem layout (floats): [0..1023] rwc(float4[4][64]) | [1024..2047] wrc |
  // [2048..2303] rwr | [2304..2559] wrr | [4096..4607] rowout[8][64]
  // after-loop: [0..4095] reused as colred float4[4tq][4r][64]
  __shared__ __align__(16) float smem[4608];
  {
    int r = t>>6, idx = t&63;
    ((float4*)smem)[r*64+idx]        = ((const float4*)(read_w + ((size_t)b*4+r)*1024 + cc*256))[idx];
    ((float4*)(smem+1024))[r*64+idx] = ((const float4*)(wwrw   + ((size_t)b*4+r)*1024 + cc*256))[idx];
    smem[2048 + r*64+idx] = read_w[((size_t)b*4+r)*1024 + i0+idx];
    smem[2304 + r*64+idx] = wwrw  [((size_t)b*4+r)*1024 + i0+idx];
  }
  __syncthreads();
  float4 sa[4], sb[4];
  #pragma unroll
  for (int r=0;r<4;++r){ sa[r]=make_float4(0,0,0,0); sb[r]=make_float4(0,0,0,0); }
  const float4* L4 = (const float4*)L;
  size_t base4 = (size_t)b*262144 + (size_t)cc*64 + tl;
  int dcol4 = cc*64 + tl;   // global float4-col owned by this thread
  #pragma unroll 4
  for (int k=0;k<16;++k) {
    int il = tq*16 + k;
    int i = i0 + il;
    float4 lv = L4[base4 + (size_t)i*256];
    // col sums (accumulate over rows)
    #pragma unroll
    for (int r=0;r<4;++r) {
      float wr = smem[2048 + r*64 + il];
      float ur = smem[2304 + r*64 + il];
      sa[r].x += lv.x*wr; sa[r].y += lv.y*wr; sa[r].z += lv.z*wr; sa[r].w += lv.w*wr;
      sb[r].x += lv.x*ur; sb[r].y += lv.y*ur; sb[r].z += lv.z*ur; sb[r].w += lv.w*ur;
    }
    // diagonal
    if (dcol4 == (i>>2)) {
      const float* lp = (const float*)&lv;
      diag[b*1024+i] = lp[i&3];
    }
    // row dots: reduce across 64 lanes
    float pa[4], pb[4];
    #pragma unroll
    for (int r=0;r<4;++r) {
      pa[r] = dot4_(lv, ((const float4*)smem)[r*64+tl]);
      pb[r] = dot4_(lv, ((const float4*)(smem+1024))[r*64+tl]);
    }
    #pragma unroll
    for (int off=32; off; off>>=1) {
      #pragma unroll
      for (int r=0;r<4;++r) { pa[r]+=__shfl_xor(pa[r],off); pb[r]+=__shfl_xor(pb[r],off); }
    }
    if (tl==0) {
      #pragma unroll
      for (int r=0;r<4;++r) { smem[4096 + r*64 + il] = pa[r]; smem[4096 + (4+r)*64 + il] = pb[r]; }
    }
  }
  __syncthreads();
  // write row-dot partials (coalesced, wave 0)
  if (t < 64) {
    #pragma unroll
    for (int r=0;r<4;++r) {
      RAp[(((size_t)(b*4+cc))*4+r)*1024 + i0 + t] = smem[4096 + r*64 + t];
      RBp[(((size_t)(b*4+cc))*4+r)*1024 + i0 + t] = smem[4096 + (4+r)*64 + t];
    }
  }
  // col-sum reduction across the 4 waves (reuse staging region)
  #pragma unroll
  for (int r=0;r<4;++r) ((float4*)smem)[(tq*4+r)*64 + tl] = sa[r];
  __syncthreads();
  {
    int rr = t>>6, cl = t&63;
    float4 a0 = ((const float4*)smem)[(0*4+rr)*64+cl];
    float4 a1 = ((const float4*)smem)[(1*4+rr)*64+cl];
    float4 a2 = ((const float4*)smem)[(2*4+rr)*64+cl];
    float4 a3 = ((const float4*)smem)[(3*4+rr)*64+cl];
    float4 tot; tot.x=a0.x+a1.x+a2.x+a3.x; tot.y=a0.y+a1.y+a2.y+a3.y;
    tot.z=a0.z+a1.z+a2.z+a3.z; tot.w=a0.w+a1.w+a2.w+a3.w;
    ((float4*)(SAp + (((size_t)(b*16+rc))*4+rr)*1024 + cc*256))[cl] = tot;
  }
  __syncthreads();
  #pragma unroll
  for (int r=0;r<4;++r) ((float4*)smem)[(tq*4+r)*64 + tl] = sb[r];
  __syncthreads();
  {
    int rr = t>>6, cl = t&63;
    float4 a0 = ((const float4*)smem)[(0*4+rr)*64+cl];
    float4 a1 = ((const float4*)smem)[(1*4+rr)*64+cl];
    float4 a2 = ((const float4*)smem)[(2*4+rr)*64+cl];
    float4 a3 = ((const float4*)smem)[(3*4+rr)*64+cl];
    float4 tot; tot.x=a0.x+a1.x+a2.x+a3.x; tot.y=a0.y+a1.y+a2.y+a3.y;
    tot.z=a0.z+a1.z+a2.z+a3.z; tot.w=a0.w+a1.w+a2.w+a3.w;
    ((float4*)(SBp + (((size_t)(b*16+rc))*4+rr)*1024 + cc*256))[cl] = tot;
  }
}

// ---------------- K5: content softmax + combine + readout (fused) ----------------
__global__ __launch_bounds__(256) void k_read(
    const float* __restrict__ newmem, const float* __restrict__ invn,
    const float* __restrict__ rkn, const float* __restrict__ rs,
    const float* __restrict__ rm, const float* __restrict__ RAp,
    const float* __restrict__ RBp, const float* __restrict__ SAp,
    const float* __restrict__ SBp, const float* __restrict__ ww,
    const float* __restrict__ precedence, const float* __restrict__ read_w,
    const float* __restrict__ diag, const float* __restrict__ prd,
    const float* __restrict__ wrd, float* __restrict__ out) {
  int b=blockIdx.x, r=blockIdx.y;
  int t=threadIdx.x, lane=t&63, wave=t>>6;
  int lane16 = t & 15, rl = t >> 4;
  __shared__ __align__(16) float s_key[64];
  __shared__ float s_arr[1024];
  __shared__ float s_red[4];
  __shared__ float s_bc[2];
  __shared__ __align__(16) float4 s_acc[16][16];
  if (t<64) s_key[t]=rkn[((size_t)b*4+r)*64+t];
  __syncthreads();
  float rstr = rs[b*4+r];
  float4 key4 = ((const float4*)s_key)[lane16];
  for (int p=0;p<64;++p) {
    int row = p*16 + rl;
    float4 m4 = ((const float4*)newmem)[((size_t)b*1024+row)*16 + lane16];
    float d = dot4_(m4, key4);
    d += __shfl_xor(d,1); d += __shfl_xor(d,2);
    d += __shfl_xor(d,4); d += __shfl_xor(d,8);
    if (lane16==0) s_arr[row] = d * invn[b*1024+row] * rstr;
  }
  __syncthreads();
  {
    float lm=-1e30f;
    for (int n=t;n<1024;n+=256) lm=fmaxf(lm,s_arr[n]);
    for (int off=32;off;off>>=1) lm=fmaxf(lm,__shfl_xor(lm,off));
    if (lane==0) s_red[wave]=lm;
    __syncthreads();
    if (t==0) s_bc[0]=fmaxf(fmaxf(s_red[0],s_red[1]),fmaxf(s_red[2],s_red[3]));
    __syncthreads();
    float mx=s_bc[0], ls=0.f;
    for (int n=t;n<1024;n+=256){ float e=expf(s_arr[n]-mx); s_arr[n]=e; ls+=e; }
    for (int off=32;off;off>>=1) ls+=__shfl_xor(ls,off);
    if (lane==0) s_red[wave]=ls;
    __syncthreads();
    if (t==0) s_bc[1]=s_red[0]+s_red[1]+s_red[2]+s_red[3];
    __syncthreads();
    float inv=1.f/s_bc[1];
    for (int n=t;n<1024;n+=256) s_arr[n]*=inv;
  }
  __syncthreads();
  float m0=rm[b*12+r*3+0], m1=rm[b*12+r*3+1], m2=rm[b*12+r*3+2];
  float pd=prd[b*4+r], wd=wrd[b*4+r];
  for (int n=t;n<1024;n+=256) {
    float ra=0.f, rb=0.f;
    #pragma unroll
    for (int cc=0;cc<4;++cc){
      ra += RAp[(((size_t)(b*4+cc))*4+r)*1024+n];
      rb += RBp[(((size_t)(b*4+cc))*4+r)*1024+n];
    }
    float sa=0.f, sb=0.f;
    #pragma unroll
    for (int rc=0;rc<16;++rc){
      sa+=SAp[(((size_t)(b*16+rc))*4+r)*1024+n];
      sb+=SBp[(((size_t)(b*16+rc))*4+r)*1024+n];
    }
    float w_ = ww[b*1024+n];
    float pn = precedence[b*1024+n];
    float rwv= read_w[((size_t)b*4+r)*1024+n];
    float dg = diag[b*1024+n];
    float fwd = (1.f-w_)*ra - rb + w_*pd - ((1.f-2.f*w_)*dg + w_*pn)*rwv;
    float bwd = (1.f-w_)*sa - sb + pn*(wd - w_*rwv) - (1.f-2.f*w_)*dg*rwv;
    float crw = s_arr[n];
    __syncthreads();
    s_arr[n] = m0*bwd + m1*crw + m2*fwd;
    __syncthreads();
  }
  __syncthreads();
  float4 acc = {0,0,0,0};
  for (int p=0;p<64;++p) {
    int row = p*16 + rl;
    float4 m4 = ((const float4*)newmem)[((size_t)b*1024+row)*16 + lane16];
    float s = s_arr[row];
    acc.x += s*m4.x; acc.y += s*m4.y; acc.z += s*m4.z; acc.w += s*m4.w;
  }
  s_acc[rl][lane16] = acc;
  __syncthreads();
  if (t < 16) {
    float4 tot = {0,0,0,0};
    #pragma unroll
    for (int g=0; g<16; ++g) {
      float4 v = s_acc[g][t];
      tot.x+=v.x; tot.y+=v.y; tot.z+=v.z; tot.w+=v.w;
    }
    ((float4*)(out + (b*4+r)*64))[t] = tot;
  }
}

extern "C" void kernel_launch(void* const* d_in, const int* in_sizes, int n_in,
                              void* d_out, int out_size, void* d_ws, size_t ws_size,
                              hipStream_t stream) {
  const float* x      = (const float*)d_in[0];
  const float* W_if   = (const float*)d_in[1];
  const float* b_if   = (const float*)d_in[2];
  const float* memory = (const float*)d_in[3];
  const float* link   = (const float*)d_in[4];
  const float* prec   = (const float*)d_in[5];
  const float* read_w = (const float*)d_in[6];
  const float* write_w= (const float*)d_in[7];
  const float* usage  = (const float*)d_in[8];
  float* out = (float*)d_out;
  float* ws = (float*)d_ws;

  float* xi   = ws + OFF_XI;
  float* rkn  = ws + OFF_RKN;
  float* rs   = ws + OFF_RS;
  float* er   = ws + OFF_ER;
  float* wv   = ws + OFF_WV;
  float* rm   = ws + OFF_RM;
  float* wwp  = ws + OFF_WW;
  float* wwrw = ws + OFF_WWRW;
  float* prd  = ws + OFF_PRD;
  float* wrd  = ws + OFF_WRD;
  float* invn = ws + OFF_INVN;
  float* diag = ws + OFF_DIAG;
  float* nm   = ws + OFF_NM;
  float* RAp  = ws + OFF_RAP;
  float* RBp  = ws + OFF_RBP;
  float* SAp  = ws + OFF_SAP;
  float* SBp  = ws + OFF_SBP;

  k_xi<<<dim3(32,8), 256, 0, stream>>>(x, W_if, b_if, xi);
  k_batch<<<dim3(32), 256, 0, stream>>>(xi, memory, usage, read_w, write_w, prec,
                                        rkn, rs, er, wv, rm, wwp, wwrw, prd, wrd);
  k_newmem<<<dim3(32,16), 256, 0, stream>>>(memory, wwp, er, wv, nm, invn);
  k_scan<<<dim3(32,16,4), 256, 0, stream>>>(link, read_w, wwrw, RAp, RBp, SAp, SBp, diag);
  k_read<<<dim3(32,4), 256, 0, stream>>>(nm, invn, rkn, rs, rm, RAp, RBp, SAp, SBp,
                                         wwp, prec, read_w, diag, prd, wrd, out);
}

// Round 5
// 371.303 us; speedup vs baseline: 1.1080x; 1.1080x over previous
//
#include <hip/hip_runtime.h>
#include <math.h>

#define DELTA_ 1e-6f
#define IFACE_ 471
#define XI_STRIDE 480

// workspace offsets (in floats)
#define OFF_XI    0            // 32*480
#define OFF_RKN   15360        // 32*4*64
#define OFF_RS    23552        // 32*4
#define OFF_ER    23680        // 32*64
#define OFF_WV    25728        // 32*64
#define OFF_RM    27776        // 32*12
#define OFF_WW    28160        // 32*1024
#define OFF_WWRW  60928        // 32*4*1024
#define OFF_PRD   192000       // 32*4
#define OFF_WRD   192128       // 32*4
#define OFF_INVN  192256       // 32*1024
#define OFF_DIAG  225024       // 32*1024
#define OFF_NM    257792       // 32*1024*64
#define OFF_RAP   2354944      // 32*2cc*4r*1024
#define OFF_RBP   2617088      // 32*2cc*4r*1024
#define OFF_SAP   2879232      // 32*16rc*4r*1024
#define OFF_SBP   4976384      // 32*16rc*4r*1024
// total 7073536 floats = 27 MB

__device__ __forceinline__ float sigm_(float x){ return 1.f/(1.f+expf(-x)); }
__device__ __forceinline__ float softp_(float x){ return fmaxf(x,0.f)+log1pf(expf(-fabsf(x))); }
__device__ __forceinline__ float dot4_(float4 a, float4 b){ return a.x*b.x+a.y*b.y+a.z*b.z+a.w*b.w; }

// ---------------- K1: xi = x @ W_if + b_if ----------------
__global__ __launch_bounds__(256) void k_xi(const float* __restrict__ x,
    const float* __restrict__ W, const float* __restrict__ bias,
    float* __restrict__ xi) {
  int b = blockIdx.x;
  int j0 = blockIdx.y*64;
  int t = threadIdx.x;
  int jl = t & 63, kq = t >> 6;
  __shared__ __align__(16) float sx[1024];
  __shared__ float s_part[256];
  for (int q=t; q<256; q+=256) ((float4*)sx)[q] = ((const float4*)(x + b*1024))[q];
  __syncthreads();
  int j = j0 + jl;
  int jc = j < IFACE_ ? j : IFACE_-1;
  float acc = 0.f;
  const float* Wp = W + (size_t)kq*256*IFACE_ + jc;
  #pragma unroll 4
  for (int k=0;k<256;++k) acc += sx[kq*256+k]*Wp[(size_t)k*IFACE_];
  s_part[t] = acc;
  __syncthreads();
  if (t < 64 && (j0+t) < IFACE_) {
    xi[b*XI_STRIDE + j0+t] = s_part[t]+s_part[64+t]+s_part[128+t]+s_part[192+t] + bias[j0+t];
  }
}

// ---------------- K2: per-batch: activations, wcw, usage, sort/alloc, ww ----------------
__global__ __launch_bounds__(256) void k_batch(
    const float* __restrict__ xi, const float* __restrict__ memory,
    const float* __restrict__ usage, const float* __restrict__ read_w,
    const float* __restrict__ write_w, const float* __restrict__ precedence,
    float* __restrict__ rkn, float* __restrict__ rs, float* __restrict__ er,
    float* __restrict__ wv, float* __restrict__ rm, float* __restrict__ ww_out,
    float* __restrict__ wwrw, float* __restrict__ prd, float* __restrict__ wrd) {
  int b = blockIdx.x; int t = threadIdx.x;
  int lane = t & 63; int wave = t >> 6;
  __shared__ float s_act[472];
  __shared__ __align__(16) float s_key[64];
  __shared__ float s_wcw[1024];
  __shared__ unsigned long long s_k64[1024];
  __shared__ float s_ps[1024];
  __shared__ float s_alloc[1024];
  __shared__ float s_red[32];
  __shared__ float s_bc[2];

  for (int q = t; q < IFACE_; q += 256) {
    float v = xi[b*XI_STRIDE+q];
    float a;
    if      (q < 256) a = tanhf(v);
    else if (q < 260) a = softp_(v);
    else if (q < 324) a = tanhf(v);
    else if (q < 325) a = softp_(v);
    else if (q < 389) a = sigm_(v);
    else if (q < 453) a = tanhf(v);
    else if (q < 459) a = sigm_(v);
    else              a = v;
    s_act[q] = a;
  }
  __syncthreads();
  if (t < 4) {
    float m0=s_act[459+3*t], m1=s_act[460+3*t], m2=s_act[461+3*t];
    float mx=fmaxf(m0,fmaxf(m1,m2));
    float e0=expf(m0-mx), e1=expf(m1-mx), e2=expf(m2-mx);
    float s=e0+e1+e2;
    rm[b*12+3*t+0]=e0/s; rm[b*12+3*t+1]=e1/s; rm[b*12+3*t+2]=e2/s;
  }
  if (t < 64) { er[b*64+t]=s_act[325+t]; wv[b*64+t]=s_act[389+t]; }
  {
    int r = wave;
    float v = s_act[r*64+lane];
    float ss = v*v;
    for (int off=32; off; off>>=1) ss += __shfl_xor(ss, off);
    rkn[((size_t)b*4+r)*64+lane] = v / (sqrtf(ss)+DELTA_);
    if (lane==0) rs[b*4+r] = s_act[256+r];
  }
  if (wave==0) {
    float v = s_act[260+lane];
    float ss=v*v;
    for (int off=32; off; off>>=1) ss += __shfl_xor(ss, off);
    s_key[lane] = v/(sqrtf(ss)+DELTA_);
  }
  __syncthreads();
  float wstr = s_act[324], agv = s_act[457], wgv = s_act[458];

  for (int n=t; n<1024; n+=256) {
    const float4* row = (const float4*)(memory + ((size_t)b*1024+n)*64);
    float dot=0.f, nn2=0.f;
    #pragma unroll
    for (int w4=0; w4<16; ++w4) {
      float4 m4 = row[w4];
      float4 k4 = ((const float4*)s_key)[w4];
      dot += dot4_(m4,k4);
      nn2 += dot4_(m4,m4);
    }
    s_wcw[n] = dot/(sqrtf(nn2)+DELTA_) * wstr;
  }
  __syncthreads();
  {
    float lm=-1e30f;
    for (int n=t;n<1024;n+=256) lm=fmaxf(lm,s_wcw[n]);
    for (int off=32;off;off>>=1) lm=fmaxf(lm,__shfl_xor(lm,off));
    if (lane==0) s_red[wave]=lm;
    __syncthreads();
    if (t==0) s_bc[0]=fmaxf(fmaxf(s_red[0],s_red[1]),fmaxf(s_red[2],s_red[3]));
    __syncthreads();
    float mx=s_bc[0], ls=0.f;
    for (int n=t;n<1024;n+=256){ float e=expf(s_wcw[n]-mx); s_wcw[n]=e; ls+=e; }
    for (int off=32;off;off>>=1) ls+=__shfl_xor(ls,off);
    if (lane==0) s_red[wave]=ls;
    __syncthreads();
    if (t==0) s_bc[1]=s_red[0]+s_red[1]+s_red[2]+s_red[3];
    __syncthreads();
    float inv=1.f/s_bc[1];
    for (int n=t;n<1024;n+=256) s_wcw[n]*=inv;
  }
  __syncthreads();

  for (int n=t; n<1024; n+=256) {
    float us = usage[b*1024+n];
    float wwi = write_w[b*1024+n];
    float u = us + (1.f-us)*wwi;
    float psi = 1.f;
    #pragma unroll
    for (int r=0;r<4;++r) psi *= (1.f - s_act[453+r]*read_w[((size_t)b*4+r)*1024+n]);
    u *= psi;
    u = DELTA_ + (1.f-DELTA_)*u;
    unsigned int ub = __float_as_uint(u);
    s_k64[n] = ((unsigned long long)ub<<32) | (unsigned int)n;
  }

  for (int k=2; k<=1024; k<<=1) {
    for (int j=k>>1; j>0; j>>=1) {
      __syncthreads();
      for (int idx=t; idx<1024; idx+=256) {
        int partner = idx ^ j;
        if (partner > idx) {
          unsigned long long a=s_k64[idx], c=s_k64[partner];
          bool asc = ((idx & k) == 0);
          bool sw = asc ? (a > c) : (a < c);
          if (sw) { s_k64[idx]=c; s_k64[partner]=a; }
        }
      }
    }
  }
  __syncthreads();

  for (int n=t;n<1024;n+=256) s_ps[n] = __uint_as_float((unsigned int)(s_k64[n]>>32));
  __syncthreads();
  for (int off=1; off<1024; off<<=1) {
    float tmp[4];
    #pragma unroll
    for (int m=0;m<4;++m){ int n=t+256*m; tmp[m] = (n>=off)? s_ps[n-off] : 1.f; }
    __syncthreads();
    #pragma unroll
    for (int m=0;m<4;++m){ int n=t+256*m; s_ps[n] *= tmp[m]; }
    __syncthreads();
  }
  for (int n=t;n<1024;n+=256) {
    unsigned long long kv = s_k64[n];
    float su = __uint_as_float((unsigned int)(kv>>32));
    int oi = (int)(kv & 0xffffffffu);
    float prod = (n==0)?1.f:s_ps[n-1];
    s_alloc[oi] = (1.f-su)*prod;
  }
  __syncthreads();

  float pp[4]={0,0,0,0}, wp[4]={0,0,0,0};
  for (int n=t;n<1024;n+=256) {
    float w_ = wgv*(agv*s_alloc[n] + (1.f-agv)*s_wcw[n]);
    ww_out[b*1024+n]=w_;
    float pn = precedence[b*1024+n];
    #pragma unroll
    for (int r=0;r<4;++r){
      float rwv = read_w[((size_t)b*4+r)*1024+n];
      wwrw[((size_t)b*4+r)*1024+n] = w_*rwv;
      pp[r] += pn*rwv;
      wp[r] += w_*rwv;
    }
  }
  #pragma unroll
  for (int r=0;r<4;++r){
    for (int off=32;off;off>>=1){ pp[r]+=__shfl_xor(pp[r],off); wp[r]+=__shfl_xor(wp[r],off); }
  }
  if (lane==0){
    #pragma unroll
    for (int r=0;r<4;++r){ s_red[wave*8+r]=pp[r]; s_red[wave*8+4+r]=wp[r]; }
  }
  __syncthreads();
  if (t<4)              prd[b*4+t]   = s_red[t]+s_red[8+t]+s_red[16+t]+s_red[24+t];
  else if (t<8){ int r=t-4; wrd[b*4+r] = s_red[4+r]+s_red[12+r]+s_red[20+r]+s_red[28+r]; }
}

// ---------------- K3: new memory + row inverse norms ----------------
__global__ __launch_bounds__(256) void k_newmem(const float* __restrict__ memory,
    const float* __restrict__ ww, const float* __restrict__ er,
    const float* __restrict__ wv, float* __restrict__ newmem, float* __restrict__ invn) {
  int b = blockIdx.x;
  int n0 = blockIdx.y*64;
  int t = threadIdx.x;
  int lane16 = t & 15, rl = t >> 4;
  __shared__ float s_ww[64];
  __shared__ __align__(16) float s_er[64];
  __shared__ __align__(16) float s_wv[64];
  if (t < 64) s_ww[t] = ww[b*1024 + n0 + t];
  else if (t < 128) s_er[t-64] = er[b*64 + (t-64)];
  else if (t < 192) s_wv[t-128] = wv[b*64 + (t-128)];
  __syncthreads();
  float4 e4 = ((const float4*)s_er)[lane16];
  float4 v4 = ((const float4*)s_wv)[lane16];
  #pragma unroll
  for (int p=0;p<4;++p) {
    int rloc = p*16 + rl;
    int row = n0 + rloc;
    float wn = s_ww[rloc];
    size_t i4 = ((size_t)b*1024+row)*16 + lane16;
    float4 m4 = ((const float4*)memory)[i4];
    float4 nv;
    nv.x = m4.x*(1.f-wn*e4.x) + wn*v4.x;
    nv.y = m4.y*(1.f-wn*e4.y) + wn*v4.y;
    nv.z = m4.z*(1.f-wn*e4.z) + wn*v4.z;
    nv.w = m4.w*(1.f-wn*e4.w) + wn*v4.w;
    ((float4*)newmem)[i4] = nv;
    float ss = dot4_(nv,nv);
    ss += __shfl_xor(ss,1); ss += __shfl_xor(ss,2);
    ss += __shfl_xor(ss,4); ss += __shfl_xor(ss,8);
    if (lane16==0) invn[b*1024+row] = 1.f/(sqrtf(ss)+DELTA_);
  }
}

// ---------------- K4: single-pass L scan, LDS double-copy tiles, NO shuffles ----------------
// grid (32 b, 16 rc, 2 cc). Block: 64 rows x 512 cols (8 tiles of 64x64).
// Thread: r = wave (0..3), lc = lane (0..63).
// Phase A: thread owns row lc -> row-dot partials for reader r (accum across tiles).
// Phase B: thread owns col lc of the tile -> col-sum partials (written per tile).
__global__ __launch_bounds__(256) void k_scan(const float* __restrict__ L,
    const float* __restrict__ read_w, const float* __restrict__ wwrw,
    float* __restrict__ RAp, float* __restrict__ RBp,
    float* __restrict__ SAp, float* __restrict__ SBp,
    float* __restrict__ diag) {
  int b = blockIdx.x, rc = blockIdx.y, cc = blockIdx.z;
  int i0 = rc*64;
  int q = threadIdx.x;
  int r = q>>6, lc = q&63;
  __shared__ __align__(16) float RM[64*68];   // row-major tile, stride 68 (17 float4)
  __shared__ __align__(16) float CM[64*68];   // transposed tile CM[c][i]
  __shared__ __align__(16) float s_wc[256], s_uc[256];  // col weights for tile [r][64]
  __shared__ __align__(16) float s_wr[256], s_ur[256];  // row weights [r][64]
  s_wr[q] = read_w[((size_t)b*4+r)*1024 + i0 + lc];
  s_ur[q] = wwrw  [((size_t)b*4+r)*1024 + i0 + lc];
  const float4* L4 = (const float4*)(L + (size_t)b*1048576);
  float4 pre[4]; float wpA, wpB;
  {
    int tc0 = cc*512;
    #pragma unroll
    for (int m=0;m<4;++m){
      int flat = q + 256*m;
      int row = flat>>4, c4 = flat&15;
      pre[m] = L4[(size_t)(i0+row)*256 + (tc0>>2) + c4];
    }
    wpA = read_w[((size_t)b*4+r)*1024 + tc0 + lc];
    wpB = wwrw  [((size_t)b*4+r)*1024 + tc0 + lc];
  }
  float pa=0.f, pb=0.f;
  for (int t=0;t<8;++t) {
    int tc0 = cc*512 + t*64;
    __syncthreads();   // previous tile's LDS reads complete
    #pragma unroll
    for (int m=0;m<4;++m){
      int flat = q + 256*m;
      int row = flat>>4, c4 = flat&15;
      ((float4*)RM)[row*17 + c4] = pre[m];
      const float* p = (const float*)&pre[m];
      #pragma unroll
      for (int j=0;j<4;++j) CM[(4*c4+j)*68 + row] = p[j];
    }
    s_wc[q] = wpA; s_uc[q] = wpB;
    __syncthreads();   // tile visible
    if (t<7){
      int nc0 = tc0 + 64;
      #pragma unroll
      for (int m=0;m<4;++m){
        int flat = q + 256*m;
        int row = flat>>4, c4 = flat&15;
        pre[m] = L4[(size_t)(i0+row)*256 + (nc0>>2) + c4];
      }
      wpA = read_w[((size_t)b*4+r)*1024 + nc0 + lc];
      wpB = wwrw  [((size_t)b*4+r)*1024 + nc0 + lc];
    }
    if (i0 == tc0 && q < 64) diag[b*1024 + i0 + q] = RM[q*68 + q];
    // phase A: row dots, accumulate across tiles
    {
      const float4* RM4 = (const float4*)RM;
      const float4* w4p = (const float4*)(s_wc + r*64);
      const float4* u4p = (const float4*)(s_uc + r*64);
      #pragma unroll
      for (int c4=0;c4<16;++c4){
        float4 a4 = RM4[lc*17 + c4];
        pa += dot4_(a4, w4p[c4]);
        pb += dot4_(a4, u4p[c4]);
      }
    }
    // phase B: col sums for this tile's 64 cols
    {
      const float4* CM4 = (const float4*)CM;
      const float4* w4p = (const float4*)(s_wr + r*64);
      const float4* u4p = (const float4*)(s_ur + r*64);
      float sa=0.f, sb=0.f;
      #pragma unroll
      for (int i4=0;i4<16;++i4){
        float4 c4v = CM4[lc*17 + i4];
        sa += dot4_(c4v, w4p[i4]);
        sb += dot4_(c4v, u4p[i4]);
      }
      SAp[(((size_t)(b*16+rc))*4+r)*1024 + tc0 + lc] = sa;
      SBp[(((size_t)(b*16+rc))*4+r)*1024 + tc0 + lc] = sb;
    }
  }
  RAp[(((size_t)(b*2+cc))*4+r)*1024 + i0 + lc] = pa;
  RBp[(((size_t)(b*2+cc))*4+r)*1024 + i0 + lc] = pb;
}

// ---------------- K5: content softmax + combine + readout (fused) ----------------
__global__ __launch_bounds__(256) void k_read(
    const float* __restrict__ newmem, const float* __restrict__ invn,
    const float* __restrict__ rkn, const float* __restrict__ rs,
    const float* __restrict__ rm, const float* __restrict__ RAp,
    const float* __restrict__ RBp, const float* __restrict__ SAp,
    const float* __restrict__ SBp, const float* __restrict__ ww,
    const float* __restrict__ precedence, const float* __restrict__ read_w,
    const float* __restrict__ diag, const float* __restrict__ prd,
    const float* __restrict__ wrd, float* __restrict__ out) {
  int b=blockIdx.x, r=blockIdx.y;
  int t=threadIdx.x, lane=t&63, wave=t>>6;
  int lane16 = t & 15, rl = t >> 4;
  __shared__ __align__(16) float s_key[64];
  __shared__ float s_arr[1024];
  __shared__ float s_red[4];
  __shared__ float s_bc[2];
  __shared__ __align__(16) float4 s_acc[16][16];
  if (t<64) s_key[t]=rkn[((size_t)b*4+r)*64+t];
  __syncthreads();
  float rstr = rs[b*4+r];
  float4 key4 = ((const float4*)s_key)[lane16];
  for (int p=0;p<64;++p) {
    int row = p*16 + rl;
    float4 m4 = ((const float4*)newmem)[((size_t)b*1024+row)*16 + lane16];
    float d = dot4_(m4, key4);
    d += __shfl_xor(d,1); d += __shfl_xor(d,2);
    d += __shfl_xor(d,4); d += __shfl_xor(d,8);
    if (lane16==0) s_arr[row] = d * invn[b*1024+row] * rstr;
  }
  __syncthreads();
  {
    float lm=-1e30f;
    for (int n=t;n<1024;n+=256) lm=fmaxf(lm,s_arr[n]);
    for (int off=32;off;off>>=1) lm=fmaxf(lm,__shfl_xor(lm,off));
    if (lane==0) s_red[wave]=lm;
    __syncthreads();
    if (t==0) s_bc[0]=fmaxf(fmaxf(s_red[0],s_red[1]),fmaxf(s_red[2],s_red[3]));
    __syncthreads();
    float mx=s_bc[0], ls=0.f;
    for (int n=t;n<1024;n+=256){ float e=expf(s_arr[n]-mx); s_arr[n]=e; ls+=e; }
    for (int off=32;off;off>>=1) ls+=__shfl_xor(ls,off);
    if (lane==0) s_red[wave]=ls;
    __syncthreads();
    if (t==0) s_bc[1]=s_red[0]+s_red[1]+s_red[2]+s_red[3];
    __syncthreads();
    float inv=1.f/s_bc[1];
    for (int n=t;n<1024;n+=256) s_arr[n]*=inv;
  }
  __syncthreads();
  float m0=rm[b*12+r*3+0], m1=rm[b*12+r*3+1], m2=rm[b*12+r*3+2];
  float pd=prd[b*4+r], wd=wrd[b*4+r];
  for (int n=t;n<1024;n+=256) {
    float ra=0.f, rb=0.f;
    #pragma unroll
    for (int cc=0;cc<2;++cc){
      ra += RAp[(((size_t)(b*2+cc))*4+r)*1024+n];
      rb += RBp[(((size_t)(b*2+cc))*4+r)*1024+n];
    }
    float sa=0.f, sb=0.f;
    #pragma unroll
    for (int rc=0;rc<16;++rc){
      sa+=SAp[(((size_t)(b*16+rc))*4+r)*1024+n];
      sb+=SBp[(((size_t)(b*16+rc))*4+r)*1024+n];
    }
    float w_ = ww[b*1024+n];
    float pn = precedence[b*1024+n];
    float rwv= read_w[((size_t)b*4+r)*1024+n];
    float dg = diag[b*1024+n];
    float fwd = (1.f-w_)*ra - rb + w_*pd - ((1.f-2.f*w_)*dg + w_*pn)*rwv;
    float bwd = (1.f-w_)*sa - sb + pn*(wd - w_*rwv) - (1.f-2.f*w_)*dg*rwv;
    float crw = s_arr[n];
    __syncthreads();
    s_arr[n] = m0*bwd + m1*crw + m2*fwd;
    __syncthreads();
  }
  __syncthreads();
  float4 acc = {0,0,0,0};
  for (int p=0;p<64;++p) {
    int row = p*16 + rl;
    float4 m4 = ((const float4*)newmem)[((size_t)b*1024+row)*16 + lane16];
    float s = s_arr[row];
    acc.x += s*m4.x; acc.y += s*m4.y; acc.z += s*m4.z; acc.w += s*m4.w;
  }
  s_acc[rl][lane16] = acc;
  __syncthreads();
  if (t < 16) {
    float4 tot = {0,0,0,0};
    #pragma unroll
    for (int g=0; g<16; ++g) {
      float4 v = s_acc[g][t];
      tot.x+=v.x; tot.y+=v.y; tot.z+=v.z; tot.w+=v.w;
    }
    ((float4*)(out + (b*4+r)*64))[t] = tot;
  }
}

extern "C" void kernel_launch(void* const* d_in, const int* in_sizes, int n_in,
                              void* d_out, int out_size, void* d_ws, size_t ws_size,
                              hipStream_t stream) {
  const float* x      = (const float*)d_in[0];
  const float* W_if   = (const float*)d_in[1];
  const float* b_if   = (const float*)d_in[2];
  const float* memory = (const float*)d_in[3];
  const float* link   = (const float*)d_in[4];
  const float* prec   = (const float*)d_in[5];
  const float* read_w = (const float*)d_in[6];
  const float* write_w= (const float*)d_in[7];
  const float* usage  = (const float*)d_in[8];
  float* out = (float*)d_out;
  float* ws = (float*)d_ws;

  float* xi   = ws + OFF_XI;
  float* rkn  = ws + OFF_RKN;
  float* rs   = ws + OFF_RS;
  float* er   = ws + OFF_ER;
  float* wv   = ws + OFF_WV;
  float* rm   = ws + OFF_RM;
  float* wwp  = ws + OFF_WW;
  float* wwrw = ws + OFF_WWRW;
  float* prd  = ws + OFF_PRD;
  float* wrd  = ws + OFF_WRD;
  float* invn = ws + OFF_INVN;
  float* diag = ws + OFF_DIAG;
  float* nm   = ws + OFF_NM;
  float* RAp  = ws + OFF_RAP;
  float* RBp  = ws + OFF_RBP;
  float* SAp  = ws + OFF_SAP;
  float* SBp  = ws + OFF_SBP;

  k_xi<<<dim3(32,8), 256, 0, stream>>>(x, W_if, b_if, xi);
  k_batch<<<dim3(32), 256, 0, stream>>>(xi, memory, usage, read_w, write_w, prec,
                                        rkn, rs, er, wv, rm, wwp, wwrw, prd, wrd);
  k_scan<<<dim3(32,16,2), 256, 0, stream>>>(link, read_w, wwrw, RAp, RBp, SAp, SBp, diag);
  k_newmem<<<dim3(32,16), 256, 0, stream>>>(memory, wwp, er, wv, nm, invn);
  k_read<<<dim3(32,4), 256, 0, stream>>>(nm, invn, rkn, rs, rm, RAp, RBp, SAp, SBp,
                                         wwp, prec, read_w, diag, prd, wrd, out);
}